// Round 5
// baseline (259.635 us; speedup 1.0000x reference)
//
#include <hip/hip_runtime.h>
#include <hip/hip_bf16.h>

// ---------------------------------------------------------------------------
// AttentionLayer: out = quirky_softmax(mask * (Q K^T)) @ V
//   denom[j] = sum_k exp(mask[j,k]*S[j,k])  (row sums of E)
//   softmax[i,j] = E[i,j] / denom[j]        (column-indexed denom!)
//   => out = E @ Vs,  Vs[j] = V[j] / denom[j]
// R5: all-fp8 GEMM pipeline. E stored as F = E-1 in fp8 (8-64x finer ULP than
// E~1.0; kills the correlated rounding bias that pushed R4 to 1.46e-3).
// out = F @ Vs + colsum(Vs)  (rank-1 ones-row correction, exact).
// ---------------------------------------------------------------------------

#define N_TOK 4096
#define D_DIM 1024
#define VS_SCALE 131072.0f        // 2^17: lifts V/denom (~1e-5) into fp8 range

typedef float f32x4 __attribute__((ext_vector_type(4)));

typedef const __attribute__((address_space(1))) char g_char;
typedef __attribute__((address_space(3))) char lds_char;

__device__ inline unsigned char f32_to_fp8(float f) {
    return (unsigned char)(__builtin_amdgcn_cvt_pk_fp8_f32(f, f, 0, false) & 0xff);
}

// ---------------------------------------------------------------------------
// x fp32 -> fp8 (blocks 0..4095, 4 elems/thread) + bias concat (4096..4107)
// ---------------------------------------------------------------------------
__global__ void cvt_and_bias(const float* __restrict__ x, unsigned char* __restrict__ x8,
                             const float* __restrict__ bq, const float* __restrict__ bk,
                             const float* __restrict__ bv, float* __restrict__ bcat) {
    int b = blockIdx.x;
    if (b < 4096) {
        int i = (b * 256 + threadIdx.x) * 4;
        float4 v = *(const float4*)(x + i);
        unsigned int lo = (unsigned int)__builtin_amdgcn_cvt_pk_fp8_f32(v.x, v.y, 0, false);
        unsigned int pk = (unsigned int)__builtin_amdgcn_cvt_pk_fp8_f32(v.z, v.w, (int)lo, true);
        *(unsigned int*)(x8 + i) = pk;
    } else {
        int i = (b - 4096) * 256 + threadIdx.x;
        if (i < 1024) bcat[i] = bq[i];
        else if (i < 2048) bcat[i] = bk[i - 1024];
        else if (i < 3072) bcat[i] = bv[i - 2048];
    }
}

// ---------------------------------------------------------------------------
// Transpose three 1024x1024 fp32 W -> fp8 [out][in], concatenated
// ---------------------------------------------------------------------------
__global__ void transpose_w3(const float* __restrict__ Wq, const float* __restrict__ Wk,
                             const float* __restrict__ Wv, unsigned char* __restrict__ outT) {
    const float* in = (blockIdx.z == 0) ? Wq : (blockIdx.z == 1) ? Wk : Wv;
    unsigned char* oT = outT + (size_t)blockIdx.z * 1024 * 1024;
    __shared__ float t[64][65];
    const int c0 = blockIdx.x * 64, r0 = blockIdx.y * 64;
    const int tid = threadIdx.x;
#pragma unroll
    for (int k = 0; k < 16; k++) {
        int lin = tid + k * 256;
        int r = lin >> 6, c = lin & 63;
        t[r][c] = in[(size_t)(r0 + r) * 1024 + c0 + c];
    }
    __syncthreads();
#pragma unroll
    for (int k = 0; k < 16; k++) {
        int lin = tid + k * 256;
        int c = lin >> 6, r = lin & 63;
        oT[(size_t)(c0 + c) * 1024 + r0 + r] = f32_to_fp8(t[r][c]);
    }
}

// ---------------------------------------------------------------------------
// VsT8[d][j] = fp8( VS_SCALE * V[j][d] / denom[j] );  colsum[d] += sum_j vs
// V bf16, row stride 1024.
// ---------------------------------------------------------------------------
__global__ void scale_transpose(const __bf16* __restrict__ V,
                                const float* __restrict__ denom,
                                unsigned char* __restrict__ VT8,
                                float* __restrict__ colsum) {
    __shared__ float t[64][65];
    __shared__ float rd[64];
    const int d0 = blockIdx.x * 64, j0 = blockIdx.y * 64;
    const int tid = threadIdx.x;
    const int lane = tid & 63;
    if (tid < 64) rd[tid] = VS_SCALE / denom[j0 + tid];
    __syncthreads();
#pragma unroll
    for (int k = 0; k < 16; k++) {
        int lin = tid + k * 256;
        int j = lin >> 6, d = lin & 63;
        t[j][d] = (float)V[(size_t)(j0 + j) * D_DIM + d0 + d] * rd[j];
    }
    __syncthreads();
#pragma unroll
    for (int k = 0; k < 16; k++) {
        // d = (tid>>6) + k*4 (wave-uniform), j = lane
        int d = (tid >> 6) + k * 4;
        float val = t[lane][d];
        VT8[(size_t)(d0 + d) * N_TOK + j0 + lane] = f32_to_fp8(val);
#pragma unroll
        for (int m = 1; m < 64; m <<= 1) val += __shfl_xor(val, m, 64);
        if (lane == 0) atomicAdd(&colsum[d0 + d], val);
    }
}

// ---------------------------------------------------------------------------
// Unified fp8 NT GEMM: C = A * B^T, fp8 e4m3 in, fp32 acc, BK=128.
// 128 x TN tile, 4 waves as 2x2, each 64 x TN/2 (4 x NF frags of 16x16x32).
// LDS: row = 128 B = 8 x 16B chunks; chunk q of row r stored at q^(r&7)
// (XOR swizzle, conflict-free; staging source address carries the swizzle).
// EPI 0 (QKV):  cols<2048 -> QK8 fp8 (+bias), else -> Vb bf16 (+bias)
// EPI 1 (E):    e=exp(mask*acc); F8=fp8(e-1); denom[row]+=rowsum(e) atomics
// EPI 2 (out):  C = (acc + colsum[col]) / VS_SCALE
// ---------------------------------------------------------------------------
template <int EPI, int TN>
__global__ __launch_bounds__(256, 2)
void gemm_fp8(const unsigned char* __restrict__ A, const unsigned char* __restrict__ B,
              int sA, int sB, int K,               // row strides in BYTES
              const float* __restrict__ bias,
              const float* __restrict__ mask,
              unsigned char* __restrict__ QK8, __bf16* __restrict__ Vb,
              unsigned char* __restrict__ F8, float* __restrict__ denom,
              const float* __restrict__ colsum, float* __restrict__ C) {
    constexpr int NF = TN / 32;                    // B frags per wave
    constexpr int BP = TN / 32;                    // B staging passes
    __shared__ unsigned char lA[128 * 128];
    __shared__ unsigned char lB[TN * 128];

    const int tid  = threadIdx.x;
    const int wave = tid >> 6;
    const int lane = tid & 63;
    const int quad = lane >> 4;
    const int l16  = lane & 15;
    const int m0 = blockIdx.y * 128;
    const int n0 = blockIdx.x * TN;
    const int wr = (wave >> 1) * 64;
    const int wc = (wave & 1) * (TN / 2);

    // staging source (swizzled): thread handles row tr, 16B chunk (tid&7)^(tr&7)
    const int tr = tid >> 3;
    const int ts = ((tid & 7) ^ (tr & 7)) * 16;
    const char* gA = (const char*)A + (size_t)(m0 + tr) * sA + ts;
    const char* gB = (const char*)B + (size_t)(n0 + tr) * sB + ts;
    const size_t pstepA = (size_t)32 * sA;
    const size_t pstepB = (size_t)32 * sB;

    lds_char* lAp = (lds_char*)(void*)lA + wave * 1024;
    lds_char* lBp = (lds_char*)(void*)lB + wave * 1024;

    // LDS read offsets: kstep k reads 8 B at row byte (k*32 + quad*8);
    // chunk = k*2 + (quad>>1), swizzled ^ (l16&7), sub-offset (quad&1)*8.
    const int l7 = l16 & 7;
    const int qhi = quad >> 1, qlo = (quad & 1) * 8;
    int rd[4];
#pragma unroll
    for (int k = 0; k < 4; k++) rd[k] = ((k * 2 + qhi) ^ l7) * 16 + qlo;

    f32x4 acc[4][NF];
#pragma unroll
    for (int i = 0; i < 4; i++)
#pragma unroll
        for (int j = 0; j < NF; j++) acc[i][j] = (f32x4){0.f, 0.f, 0.f, 0.f};

    for (int kt = 0; kt < K; kt += 128) {
#pragma unroll
        for (int c = 0; c < 4; c++)
            __builtin_amdgcn_global_load_lds((g_char*)(gA + c * pstepA),
                                             lAp + c * 4096, 16, 0, 0);
#pragma unroll
        for (int c = 0; c < BP; c++)
            __builtin_amdgcn_global_load_lds((g_char*)(gB + c * pstepB),
                                             lBp + c * 4096, 16, 0, 0);
        gA += 128;
        gB += 128;
        __syncthreads();

#pragma unroll
        for (int k = 0; k < 4; k++) {
            long a[4], b[NF];
#pragma unroll
            for (int i = 0; i < 4; i++)
                a[i] = *(const long*)&lA[(wr + i * 16 + l16) * 128 + rd[k]];
#pragma unroll
            for (int j = 0; j < NF; j++)
                b[j] = *(const long*)&lB[(wc + j * 16 + l16) * 128 + rd[k]];
#pragma unroll
            for (int i = 0; i < 4; i++)
#pragma unroll
                for (int j = 0; j < NF; j++)
                    acc[i][j] = __builtin_amdgcn_mfma_f32_16x16x32_fp8_fp8(
                        a[i], b[j], acc[i][j], 0, 0, 0);
        }
        __syncthreads();
    }

    // epilogue: C/D layout col=lane&15, row=quad*4+reg
#pragma unroll
    for (int i = 0; i < 4; i++) {
        const int rbase = m0 + wr + i * 16 + quad * 4;
        f32x4 rs = (f32x4){0.f, 0.f, 0.f, 0.f};
#pragma unroll
        for (int j = 0; j < NF; j++) {
            const int col = n0 + wc + j * 16 + l16;
            f32x4 v = acc[i][j];
            if (EPI == 0) {
                const float bb = bias[col];
                if (n0 < 2048) {   // Q/K region -> fp8, row stride 2048
#pragma unroll
                    for (int r = 0; r < 4; r++)
                        QK8[(size_t)(rbase + r) * 2048 + col] = f32_to_fp8(v[r] + bb);
                } else {           // V region -> bf16, row stride 1024
#pragma unroll
                    for (int r = 0; r < 4; r++)
                        Vb[(size_t)(rbase + r) * 1024 + (col - 2048)] = (__bf16)(v[r] + bb);
                }
            } else if (EPI == 1) {
#pragma unroll
                for (int r = 0; r < 4; r++) {
                    size_t idx = (size_t)(rbase + r) * N_TOK + col;
                    float e = __expf(mask[idx] * v[r]);
                    F8[idx] = f32_to_fp8(e - 1.0f);
                    rs[r] += e;
                }
            } else {
#pragma unroll
                for (int r = 0; r < 4; r++)
                    C[(size_t)(rbase + r) * D_DIM + col] =
                        (v[r] + colsum[col]) * (1.0f / VS_SCALE);
            }
        }
        if (EPI == 1) {
#pragma unroll
            for (int m = 1; m < 16; m <<= 1) {
#pragma unroll
                for (int r = 0; r < 4; r++) rs[r] += __shfl_xor(rs[r], m, 64);
            }
            if (l16 == 0) {
#pragma unroll
                for (int r = 0; r < 4; r++) atomicAdd(&denom[rbase + r], rs[r]);
            }
        }
    }
}

// ---------------------------------------------------------------------------
extern "C" void kernel_launch(void* const* d_in, const int* in_sizes, int n_in,
                              void* d_out, int out_size, void* d_ws, size_t ws_size,
                              hipStream_t stream) {
    const float* x    = (const float*)d_in[0];
    const float* mask = (const float*)d_in[1];
    const float* Wq   = (const float*)d_in[2];
    const float* bq   = (const float*)d_in[3];
    const float* Wk   = (const float*)d_in[4];
    const float* bk   = (const float*)d_in[5];
    const float* Wv   = (const float*)d_in[6];
    const float* bv   = (const float*)d_in[7];
    float* out = (float*)d_out;
    char* ws = (char*)d_ws;

    const size_t MB = 1024 * 1024;
    unsigned char* F8   = (unsigned char*)(ws + 0 * MB);   // 16 MB [4096][4096] fp8 (E-1)
    unsigned char* QK8  = (unsigned char*)(ws + 16 * MB);  // 8 MB [4096][2048] fp8
    __bf16*        Vb   = (__bf16*)(ws + 24 * MB);         // 8 MB [4096][1024] bf16
    unsigned char* x8   = (unsigned char*)(ws + 32 * MB);  // 4 MB [4096][1024] fp8
    unsigned char* VsT8 = x8;                              // 4 MB (reuse; x8 dead after QKV)
    unsigned char* W8T  = (unsigned char*)(ws + 36 * MB);  // 3 MB [3072][1024] fp8
    float* bcat   = (float*)(ws + 39 * MB);                // 12 KB
    float* denom  = (float*)(ws + 39 * MB + 16 * 1024);    // 16 KB [4096]
    float* colsum = (float*)(ws + 39 * MB + 32 * 1024);    // 4 KB [1024]

    // zero denom + colsum (contiguous 20 KB)
    hipMemsetAsync(denom, 0, 20 * 1024, stream);

    // ---- prep ----
    cvt_and_bias<<<4096 + 12, 256, 0, stream>>>(x, x8, bq, bk, bv, bcat);
    transpose_w3<<<dim3(16, 16, 3), 256, 0, stream>>>(Wq, Wk, Wv, W8T);

    // ---- fused QKV projection: [4096][3072] = x8 @ W8T^T + bcat ----
    gemm_fp8<0, 128><<<dim3(24, 32), 256, 0, stream>>>(
        x8, W8T, 1024, 1024, D_DIM,
        bcat, nullptr, QK8, Vb, nullptr, nullptr, nullptr, nullptr);

    // ---- F = exp(mask * (Q K^T)) - 1 -> fp8; denom[row] += rowsum(e) ----
    gemm_fp8<1, 128><<<dim3(32, 32), 256, 0, stream>>>(
        QK8, QK8 + 1024, 2048, 2048, D_DIM,
        nullptr, mask, nullptr, nullptr, F8, denom, nullptr, nullptr);

    // ---- VsT8[d][j] = fp8(VS_SCALE * V[j][d]/denom[j]); colsum[d] = sum_j ----
    scale_transpose<<<dim3(16, 64), 256, 0, stream>>>(Vb, denom, VsT8, colsum);

    // ---- out = (F8 @ VsT8^T + colsum) / VS_SCALE ----
    gemm_fp8<2, 64><<<dim3(16, 32), 256, 0, stream>>>(
        F8, VsT8, 4096, 4096, N_TOK,
        nullptr, nullptr, nullptr, nullptr, nullptr, nullptr, colsum, out);
}

// Round 6
// 252.248 us; speedup vs baseline: 1.0293x; 1.0293x over previous
//
#include <hip/hip_runtime.h>
#include <hip/hip_bf16.h>

// ---------------------------------------------------------------------------
// AttentionLayer: out = quirky_softmax(mask * (Q K^T)) @ V
//   denom[j] = sum_k exp(mask[j,k]*S[j,k])  (row sums of E)
//   softmax[i,j] = E[i,j] / denom[j]        (column-indexed denom!)
//   => out = E @ Vs,  Vs[j] = V[j] / denom[j]
// R5->R6: fp8 K-loop reads ds_read_b128 (R3's proven conflict-free bank
// pattern) via K-permutation: chunk 4q+m of each 128B row feeds MFMA m at
// quad q (commutative over K; same assignment for A and B). b64 reads were
// costing +4 cyc/read (SQ_LDS_BANK_CONFLICT=4.2M). Occupancy floor 4/SIMD.
// ---------------------------------------------------------------------------

#define N_TOK 4096
#define D_DIM 1024
#define VS_SCALE 131072.0f        // 2^17: lifts V/denom (~1e-5) into fp8 range

typedef float f32x4 __attribute__((ext_vector_type(4)));
typedef long  longx2 __attribute__((ext_vector_type(2)));

typedef const __attribute__((address_space(1))) char g_char;
typedef __attribute__((address_space(3))) char lds_char;

__device__ inline unsigned char f32_to_fp8(float f) {
    return (unsigned char)(__builtin_amdgcn_cvt_pk_fp8_f32(f, f, 0, false) & 0xff);
}

// ---------------------------------------------------------------------------
// x fp32 -> fp8 (blocks 0..4095, 4 elems/thread) + bias concat (4096..4107)
// ---------------------------------------------------------------------------
__global__ void cvt_and_bias(const float* __restrict__ x, unsigned char* __restrict__ x8,
                             const float* __restrict__ bq, const float* __restrict__ bk,
                             const float* __restrict__ bv, float* __restrict__ bcat) {
    int b = blockIdx.x;
    if (b < 4096) {
        int i = (b * 256 + threadIdx.x) * 4;
        float4 v = *(const float4*)(x + i);
        unsigned int lo = (unsigned int)__builtin_amdgcn_cvt_pk_fp8_f32(v.x, v.y, 0, false);
        unsigned int pk = (unsigned int)__builtin_amdgcn_cvt_pk_fp8_f32(v.z, v.w, (int)lo, true);
        *(unsigned int*)(x8 + i) = pk;
    } else {
        int i = (b - 4096) * 256 + threadIdx.x;
        if (i < 1024) bcat[i] = bq[i];
        else if (i < 2048) bcat[i] = bk[i - 1024];
        else if (i < 3072) bcat[i] = bv[i - 2048];
    }
}

// ---------------------------------------------------------------------------
// Transpose three 1024x1024 fp32 W -> fp8 [out][in], concatenated
// ---------------------------------------------------------------------------
__global__ void transpose_w3(const float* __restrict__ Wq, const float* __restrict__ Wk,
                             const float* __restrict__ Wv, unsigned char* __restrict__ outT) {
    const float* in = (blockIdx.z == 0) ? Wq : (blockIdx.z == 1) ? Wk : Wv;
    unsigned char* oT = outT + (size_t)blockIdx.z * 1024 * 1024;
    __shared__ float t[64][65];
    const int c0 = blockIdx.x * 64, r0 = blockIdx.y * 64;
    const int tid = threadIdx.x;
#pragma unroll
    for (int k = 0; k < 16; k++) {
        int lin = tid + k * 256;
        int r = lin >> 6, c = lin & 63;
        t[r][c] = in[(size_t)(r0 + r) * 1024 + c0 + c];
    }
    __syncthreads();
#pragma unroll
    for (int k = 0; k < 16; k++) {
        int lin = tid + k * 256;
        int c = lin >> 6, r = lin & 63;
        oT[(size_t)(c0 + c) * 1024 + r0 + r] = f32_to_fp8(t[r][c]);
    }
}

// ---------------------------------------------------------------------------
// VsT8[d][j] = fp8( VS_SCALE * V[j][d] / denom[j] );  colsum[d] += sum_j vs
// ---------------------------------------------------------------------------
__global__ void scale_transpose(const __bf16* __restrict__ V,
                                const float* __restrict__ denom,
                                unsigned char* __restrict__ VT8,
                                float* __restrict__ colsum) {
    __shared__ float t[64][65];
    __shared__ float rd[64];
    const int d0 = blockIdx.x * 64, j0 = blockIdx.y * 64;
    const int tid = threadIdx.x;
    const int lane = tid & 63;
    if (tid < 64) rd[tid] = VS_SCALE / denom[j0 + tid];
    __syncthreads();
#pragma unroll
    for (int k = 0; k < 16; k++) {
        int lin = tid + k * 256;
        int j = lin >> 6, d = lin & 63;
        t[j][d] = (float)V[(size_t)(j0 + j) * D_DIM + d0 + d] * rd[j];
    }
    __syncthreads();
#pragma unroll
    for (int k = 0; k < 16; k++) {
        int d = (tid >> 6) + k * 4;   // wave-uniform
        float val = t[lane][d];
        VT8[(size_t)(d0 + d) * N_TOK + j0 + lane] = f32_to_fp8(val);
#pragma unroll
        for (int m = 1; m < 64; m <<= 1) val += __shfl_xor(val, m, 64);
        if (lane == 0) atomicAdd(&colsum[d0 + d], val);
    }
}

// ---------------------------------------------------------------------------
// Unified fp8 NT GEMM: C = A * B^T, fp8 e4m3 in, fp32 acc, BK=128.
// 128 x TN tile, 4 waves as 2x2, each 64 x TN/2 (4 x NF frags of 16x16x32).
// LDS: identity row layout (128 B = 8 x 16B chunks), chunk q of row r stored
// at q^(r&7) (XOR swizzle on the staging SOURCE address; conflict-free).
// K-loop reads b128: the 16 B at swizzled chunk (quad*2+kp) feeds MFMAs
// m=2kp (.x) and m=2kp+1 (.y) -- K-permutation chunk c(m,q)=4q+m, identical
// for A and B, so the contraction is exact.
// EPI 0 (QKV):  cols<2048 -> QK8 fp8 (+bias), else -> Vb bf16 (+bias)
// EPI 1 (E):    e=exp(mask*acc); F8=fp8(e-1); denom[row]+=rowsum(e) atomics
// EPI 2 (out):  C = (acc + colsum[col]) / VS_SCALE
// ---------------------------------------------------------------------------
template <int EPI, int TN>
__global__ __launch_bounds__(256, 4)
void gemm_fp8(const unsigned char* __restrict__ A, const unsigned char* __restrict__ B,
              int sA, int sB, int K,               // row strides in BYTES
              const float* __restrict__ bias,
              const float* __restrict__ mask,
              unsigned char* __restrict__ QK8, __bf16* __restrict__ Vb,
              unsigned char* __restrict__ F8, float* __restrict__ denom,
              const float* __restrict__ colsum, float* __restrict__ C) {
    constexpr int NF = TN / 32;                    // B frags per wave
    constexpr int BP = TN / 32;                    // B staging passes
    __shared__ __align__(16) unsigned char lA[128 * 128];
    __shared__ __align__(16) unsigned char lB[TN * 128];

    const int tid  = threadIdx.x;
    const int wave = tid >> 6;
    const int lane = tid & 63;
    const int quad = lane >> 4;
    const int l16  = lane & 15;
    const int m0 = blockIdx.y * 128;
    const int n0 = blockIdx.x * TN;
    const int wr = (wave >> 1) * 64;
    const int wc = (wave & 1) * (TN / 2);

    // staging source (swizzled): thread handles row tr, 16B chunk (tid&7)^(tr&7)
    const int tr = tid >> 3;
    const int ts = ((tid & 7) ^ (tr & 7)) * 16;
    const char* gA = (const char*)A + (size_t)(m0 + tr) * sA + ts;
    const char* gB = (const char*)B + (size_t)(n0 + tr) * sB + ts;
    const size_t pstepA = (size_t)32 * sA;
    const size_t pstepB = (size_t)32 * sB;

    lds_char* lAp = (lds_char*)(void*)lA + wave * 1024;
    lds_char* lBp = (lds_char*)(void*)lB + wave * 1024;

    // b128 read offsets: kp in {0,1}; 16 B at swizzled chunk (quad*2+kp)
    const int l7 = l16 & 7;
    const int rdp0 = ((quad * 2 + 0) ^ l7) * 16;
    const int rdp1 = ((quad * 2 + 1) ^ l7) * 16;

    f32x4 acc[4][NF];
#pragma unroll
    for (int i = 0; i < 4; i++)
#pragma unroll
        for (int j = 0; j < NF; j++) acc[i][j] = (f32x4){0.f, 0.f, 0.f, 0.f};

    for (int kt = 0; kt < K; kt += 128) {
#pragma unroll
        for (int c = 0; c < 4; c++)
            __builtin_amdgcn_global_load_lds((g_char*)(gA + c * pstepA),
                                             lAp + c * 4096, 16, 0, 0);
#pragma unroll
        for (int c = 0; c < BP; c++)
            __builtin_amdgcn_global_load_lds((g_char*)(gB + c * pstepB),
                                             lBp + c * 4096, 16, 0, 0);
        gA += 128;
        gB += 128;
        __syncthreads();

#pragma unroll
        for (int kp = 0; kp < 2; kp++) {
            const int rdo = kp ? rdp1 : rdp0;
            longx2 a2[4], b2[NF];
#pragma unroll
            for (int i = 0; i < 4; i++)
                a2[i] = *(const longx2*)&lA[(wr + i * 16 + l16) * 128 + rdo];
#pragma unroll
            for (int j = 0; j < NF; j++)
                b2[j] = *(const longx2*)&lB[(wc + j * 16 + l16) * 128 + rdo];
#pragma unroll
            for (int i = 0; i < 4; i++)
#pragma unroll
                for (int j = 0; j < NF; j++)
                    acc[i][j] = __builtin_amdgcn_mfma_f32_16x16x32_fp8_fp8(
                        a2[i].x, b2[j].x, acc[i][j], 0, 0, 0);
#pragma unroll
            for (int i = 0; i < 4; i++)
#pragma unroll
                for (int j = 0; j < NF; j++)
                    acc[i][j] = __builtin_amdgcn_mfma_f32_16x16x32_fp8_fp8(
                        a2[i].y, b2[j].y, acc[i][j], 0, 0, 0);
        }
        __syncthreads();
    }

    // epilogue: C/D layout col=lane&15, row=quad*4+reg
#pragma unroll
    for (int i = 0; i < 4; i++) {
        const int rbase = m0 + wr + i * 16 + quad * 4;
        f32x4 rs = (f32x4){0.f, 0.f, 0.f, 0.f};
#pragma unroll
        for (int j = 0; j < NF; j++) {
            const int col = n0 + wc + j * 16 + l16;
            f32x4 v = acc[i][j];
            if (EPI == 0) {
                const float bb = bias[col];
                if (n0 < 2048) {   // Q/K region -> fp8, row stride 2048
#pragma unroll
                    for (int r = 0; r < 4; r++)
                        QK8[(size_t)(rbase + r) * 2048 + col] = f32_to_fp8(v[r] + bb);
                } else {           // V region -> bf16, row stride 1024
#pragma unroll
                    for (int r = 0; r < 4; r++)
                        Vb[(size_t)(rbase + r) * 1024 + (col - 2048)] = (__bf16)(v[r] + bb);
                }
            } else if (EPI == 1) {
#pragma unroll
                for (int r = 0; r < 4; r++) {
                    size_t idx = (size_t)(rbase + r) * N_TOK + col;
                    float e = __expf(mask[idx] * v[r]);
                    F8[idx] = f32_to_fp8(e - 1.0f);
                    rs[r] += e;
                }
            } else {
#pragma unroll
                for (int r = 0; r < 4; r++)
                    C[(size_t)(rbase + r) * D_DIM + col] =
                        (v[r] + colsum[col]) * (1.0f / VS_SCALE);
            }
        }
        if (EPI == 1) {
#pragma unroll
            for (int m = 1; m < 16; m <<= 1) {
#pragma unroll
                for (int r = 0; r < 4; r++) rs[r] += __shfl_xor(rs[r], m, 64);
            }
            if (l16 == 0) {
#pragma unroll
                for (int r = 0; r < 4; r++) atomicAdd(&denom[rbase + r], rs[r]);
            }
        }
    }
}

// ---------------------------------------------------------------------------
extern "C" void kernel_launch(void* const* d_in, const int* in_sizes, int n_in,
                              void* d_out, int out_size, void* d_ws, size_t ws_size,
                              hipStream_t stream) {
    const float* x    = (const float*)d_in[0];
    const float* mask = (const float*)d_in[1];
    const float* Wq   = (const float*)d_in[2];
    const float* bq   = (const float*)d_in[3];
    const float* Wk   = (const float*)d_in[4];
    const float* bk   = (const float*)d_in[5];
    const float* Wv   = (const float*)d_in[6];
    const float* bv   = (const float*)d_in[7];
    float* out = (float*)d_out;
    char* ws = (char*)d_ws;

    const size_t MB = 1024 * 1024;
    unsigned char* F8   = (unsigned char*)(ws + 0 * MB);   // 16 MB [4096][4096] fp8 (E-1)
    unsigned char* QK8  = (unsigned char*)(ws + 16 * MB);  // 8 MB [4096][2048] fp8
    __bf16*        Vb   = (__bf16*)(ws + 24 * MB);         // 8 MB [4096][1024] bf16
    unsigned char* x8   = (unsigned char*)(ws + 32 * MB);  // 4 MB [4096][1024] fp8
    unsigned char* VsT8 = x8;                              // 4 MB (reuse; x8 dead after QKV)
    unsigned char* W8T  = (unsigned char*)(ws + 36 * MB);  // 3 MB [3072][1024] fp8
    float* bcat   = (float*)(ws + 39 * MB);                // 12 KB
    float* denom  = (float*)(ws + 39 * MB + 16 * 1024);    // 16 KB [4096]
    float* colsum = (float*)(ws + 39 * MB + 32 * 1024);    // 4 KB [1024]

    // zero denom + colsum (contiguous 20 KB)
    hipMemsetAsync(denom, 0, 20 * 1024, stream);

    // ---- prep ----
    cvt_and_bias<<<4096 + 12, 256, 0, stream>>>(x, x8, bq, bk, bv, bcat);
    transpose_w3<<<dim3(16, 16, 3), 256, 0, stream>>>(Wq, Wk, Wv, W8T);

    // ---- fused QKV projection: [4096][3072] = x8 @ W8T^T + bcat ----
    gemm_fp8<0, 128><<<dim3(24, 32), 256, 0, stream>>>(
        x8, W8T, 1024, 1024, D_DIM,
        bcat, nullptr, QK8, Vb, nullptr, nullptr, nullptr, nullptr);

    // ---- F = exp(mask * (Q K^T)) - 1 -> fp8; denom[row] += rowsum(e) ----
    gemm_fp8<1, 128><<<dim3(32, 32), 256, 0, stream>>>(
        QK8, QK8 + 1024, 2048, 2048, D_DIM,
        nullptr, mask, nullptr, nullptr, F8, denom, nullptr, nullptr);

    // ---- VsT8[d][j] = fp8(VS_SCALE * V[j][d]/denom[j]); colsum[d] = sum_j ----
    scale_transpose<<<dim3(16, 64), 256, 0, stream>>>(Vb, denom, VsT8, colsum);

    // ---- out = (F8 @ VsT8^T + colsum) / VS_SCALE ----
    gemm_fp8<2, 64><<<dim3(16, 32), 256, 0, stream>>>(
        F8, VsT8, 4096, 4096, N_TOK,
        nullptr, nullptr, nullptr, nullptr, nullptr, nullptr, colsum, out);
}

// Round 7
// 249.710 us; speedup vs baseline: 1.0397x; 1.0102x over previous
//
#include <hip/hip_runtime.h>
#include <hip/hip_bf16.h>

// ---------------------------------------------------------------------------
// AttentionLayer: out = quirky_softmax(mask * (Q K^T)) @ V
//   denom[j] = sum_k exp(mask[j,k]*S[j,k])  (row sums of E)
//   softmax[i,j] = E[i,j] / denom[j]        (column-indexed denom!)
//   => out = E @ Vs,  Vs[j] = V[j] / denom[j]
// R6->R7: (1) LDS read chunk assignment kp*4+quad -> quads read an aligned
// 64B half-row ({0..3}^l7), R3's measured-zero-conflict pattern (R6's
// stride-2 set cost +1 cyc/read, SQ_LDS_BANK_CONFLICT=2.1M). (2) One fused
// prep kernel (cvt + W-transpose + bias concat + denom/colsum zeroing):
// 9 -> 6 launches.
// ---------------------------------------------------------------------------

#define N_TOK 4096
#define D_DIM 1024
#define VS_SCALE 131072.0f        // 2^17: lifts V/denom (~1e-5) into fp8 range

typedef float f32x4 __attribute__((ext_vector_type(4)));
typedef long  longx2 __attribute__((ext_vector_type(2)));

typedef const __attribute__((address_space(1))) char g_char;
typedef __attribute__((address_space(3))) char lds_char;

__device__ inline unsigned char f32_to_fp8(float f) {
    return (unsigned char)(__builtin_amdgcn_cvt_pk_fp8_f32(f, f, 0, false) & 0xff);
}

// ---------------------------------------------------------------------------
// Fused prep:
//   blocks [0,4096):    x fp32 -> fp8 (4 elems/thread)
//   blocks [4096,4864): W transpose fp32 -> fp8 [out][in] (3 x 256 tiles)
//   blocks [4864,4876): bias concat
//   blocks [4876,4896): zero denom(4096)+colsum(1024) floats
// ---------------------------------------------------------------------------
__global__ void prep(const float* __restrict__ x, unsigned char* __restrict__ x8,
                     const float* __restrict__ Wq, const float* __restrict__ Wk,
                     const float* __restrict__ Wv, unsigned char* __restrict__ W8T,
                     const float* __restrict__ bq, const float* __restrict__ bk,
                     const float* __restrict__ bv, float* __restrict__ bcat,
                     float* __restrict__ zbuf) {
    __shared__ float t[64][65];
    const int b = blockIdx.x;
    const int tid = threadIdx.x;
    if (b < 4096) {
        int i = (b * 256 + tid) * 4;
        float4 v = *(const float4*)(x + i);
        unsigned int lo = (unsigned int)__builtin_amdgcn_cvt_pk_fp8_f32(v.x, v.y, 0, false);
        unsigned int pk = (unsigned int)__builtin_amdgcn_cvt_pk_fp8_f32(v.z, v.w, (int)lo, true);
        *(unsigned int*)(x8 + i) = pk;
    } else if (b < 4864) {
        const int b2 = b - 4096;
        const int z = b2 >> 8;              // which W
        const int rem = b2 & 255;
        const float* in = (z == 0) ? Wq : (z == 1) ? Wk : Wv;
        unsigned char* oT = W8T + (size_t)z * 1024 * 1024;
        const int c0 = (rem & 15) * 64, r0 = (rem >> 4) * 64;
#pragma unroll
        for (int k = 0; k < 16; k++) {
            int lin = tid + k * 256;
            int r = lin >> 6, c = lin & 63;
            t[r][c] = in[(size_t)(r0 + r) * 1024 + c0 + c];
        }
        __syncthreads();
#pragma unroll
        for (int k = 0; k < 16; k++) {
            int lin = tid + k * 256;
            int c = lin >> 6, r = lin & 63;
            oT[(size_t)(c0 + c) * 1024 + r0 + r] = f32_to_fp8(t[r][c]);
        }
    } else if (b < 4876) {
        int i = (b - 4864) * 256 + tid;
        if (i < 1024) bcat[i] = bq[i];
        else if (i < 2048) bcat[i] = bk[i - 1024];
        else if (i < 3072) bcat[i] = bv[i - 2048];
    } else {
        zbuf[(b - 4876) * 256 + tid] = 0.0f;
    }
}

// ---------------------------------------------------------------------------
// VsT8[d][j] = fp8( VS_SCALE * V[j][d] / denom[j] );  colsum[d] += sum_j vs
// ---------------------------------------------------------------------------
__global__ void scale_transpose(const __bf16* __restrict__ V,
                                const float* __restrict__ denom,
                                unsigned char* __restrict__ VT8,
                                float* __restrict__ colsum) {
    __shared__ float t[64][65];
    __shared__ float rd[64];
    const int d0 = blockIdx.x * 64, j0 = blockIdx.y * 64;
    const int tid = threadIdx.x;
    const int lane = tid & 63;
    if (tid < 64) rd[tid] = VS_SCALE / denom[j0 + tid];
    __syncthreads();
#pragma unroll
    for (int k = 0; k < 16; k++) {
        int lin = tid + k * 256;
        int j = lin >> 6, d = lin & 63;
        t[j][d] = (float)V[(size_t)(j0 + j) * D_DIM + d0 + d] * rd[j];
    }
    __syncthreads();
#pragma unroll
    for (int k = 0; k < 16; k++) {
        int d = (tid >> 6) + k * 4;   // wave-uniform
        float val = t[lane][d];
        VT8[(size_t)(d0 + d) * N_TOK + j0 + lane] = f32_to_fp8(val);
#pragma unroll
        for (int m = 1; m < 64; m <<= 1) val += __shfl_xor(val, m, 64);
        if (lane == 0) atomicAdd(&colsum[d0 + d], val);
    }
}

// ---------------------------------------------------------------------------
// Unified fp8 NT GEMM: C = A * B^T, fp8 e4m3 in, fp32 acc, BK=128.
// 128 x TN tile, 4 waves as 2x2, each 64 x TN/2 (4 x NF frags of 16x16x32).
// LDS: row = 128 B = 8 x 16B chunks; chunk q of row r stored at q^(r&7)
// (XOR swizzle on the staging SOURCE address).
// K-loop reads b128 at swizzled position ((kp*4+quad)^l7): per row the 4
// quads cover an aligned 64B half-row -> zero bank conflicts (R3-verified).
// Logical K-chunk (kp*4+quad) feeds MFMAs 2kp (.x) / 2kp+1 (.y); same
// assignment for A and B => exact contraction (K-commutative).
// EPI 0 (QKV):  cols<2048 -> QK8 fp8 (+bias), else -> Vb bf16 (+bias)
// EPI 1 (E):    e=exp(mask*acc); F8=fp8(e-1); denom[row]+=rowsum(e) atomics
// EPI 2 (out):  C = (acc + colsum[col]) / VS_SCALE
// ---------------------------------------------------------------------------
template <int EPI, int TN>
__global__ __launch_bounds__(256, 4)
void gemm_fp8(const unsigned char* __restrict__ A, const unsigned char* __restrict__ B,
              int sA, int sB, int K,               // row strides in BYTES
              const float* __restrict__ bias,
              const float* __restrict__ mask,
              unsigned char* __restrict__ QK8, __bf16* __restrict__ Vb,
              unsigned char* __restrict__ F8, float* __restrict__ denom,
              const float* __restrict__ colsum, float* __restrict__ C) {
    constexpr int NF = TN / 32;                    // B frags per wave
    constexpr int BP = TN / 32;                    // B staging passes
    __shared__ __align__(16) unsigned char lA[128 * 128];
    __shared__ __align__(16) unsigned char lB[TN * 128];

    const int tid  = threadIdx.x;
    const int wave = tid >> 6;
    const int lane = tid & 63;
    const int quad = lane >> 4;
    const int l16  = lane & 15;
    const int m0 = blockIdx.y * 128;
    const int n0 = blockIdx.x * TN;
    const int wr = (wave >> 1) * 64;
    const int wc = (wave & 1) * (TN / 2);

    // staging source (swizzled): thread handles row tr, 16B chunk (tid&7)^(tr&7)
    const int tr = tid >> 3;
    const int ts = ((tid & 7) ^ (tr & 7)) * 16;
    const char* gA = (const char*)A + (size_t)(m0 + tr) * sA + ts;
    const char* gB = (const char*)B + (size_t)(n0 + tr) * sB + ts;
    const size_t pstepA = (size_t)32 * sA;
    const size_t pstepB = (size_t)32 * sB;

    lds_char* lAp = (lds_char*)(void*)lA + wave * 1024;
    lds_char* lBp = (lds_char*)(void*)lB + wave * 1024;

    // b128 read offsets: kp selects aligned half-row group {kp*4..kp*4+3}^l7
    const int l7 = l16 & 7;
    const int rdp0 = ((0 + quad) ^ l7) * 16;
    const int rdp1 = ((4 + quad) ^ l7) * 16;

    f32x4 acc[4][NF];
#pragma unroll
    for (int i = 0; i < 4; i++)
#pragma unroll
        for (int j = 0; j < NF; j++) acc[i][j] = (f32x4){0.f, 0.f, 0.f, 0.f};

    for (int kt = 0; kt < K; kt += 128) {
#pragma unroll
        for (int c = 0; c < 4; c++)
            __builtin_amdgcn_global_load_lds((g_char*)(gA + c * pstepA),
                                             lAp + c * 4096, 16, 0, 0);
#pragma unroll
        for (int c = 0; c < BP; c++)
            __builtin_amdgcn_global_load_lds((g_char*)(gB + c * pstepB),
                                             lBp + c * 4096, 16, 0, 0);
        gA += 128;
        gB += 128;
        __syncthreads();

#pragma unroll
        for (int kp = 0; kp < 2; kp++) {
            const int rdo = kp ? rdp1 : rdp0;
            longx2 a2[4], b2[NF];
#pragma unroll
            for (int i = 0; i < 4; i++)
                a2[i] = *(const longx2*)&lA[(wr + i * 16 + l16) * 128 + rdo];
#pragma unroll
            for (int j = 0; j < NF; j++)
                b2[j] = *(const longx2*)&lB[(wc + j * 16 + l16) * 128 + rdo];
#pragma unroll
            for (int i = 0; i < 4; i++)
#pragma unroll
                for (int j = 0; j < NF; j++)
                    acc[i][j] = __builtin_amdgcn_mfma_f32_16x16x32_fp8_fp8(
                        a2[i].x, b2[j].x, acc[i][j], 0, 0, 0);
#pragma unroll
            for (int i = 0; i < 4; i++)
#pragma unroll
                for (int j = 0; j < NF; j++)
                    acc[i][j] = __builtin_amdgcn_mfma_f32_16x16x32_fp8_fp8(
                        a2[i].y, b2[j].y, acc[i][j], 0, 0, 0);
        }
        __syncthreads();
    }

    // epilogue: C/D layout col=lane&15, row=quad*4+reg
#pragma unroll
    for (int i = 0; i < 4; i++) {
        const int rbase = m0 + wr + i * 16 + quad * 4;
        f32x4 rs = (f32x4){0.f, 0.f, 0.f, 0.f};
#pragma unroll
        for (int j = 0; j < NF; j++) {
            const int col = n0 + wc + j * 16 + l16;
            f32x4 v = acc[i][j];
            if (EPI == 0) {
                const float bb = bias[col];
                if (n0 < 2048) {   // Q/K region -> fp8, row stride 2048
#pragma unroll
                    for (int r = 0; r < 4; r++)
                        QK8[(size_t)(rbase + r) * 2048 + col] = f32_to_fp8(v[r] + bb);
                } else {           // V region -> bf16, row stride 1024
#pragma unroll
                    for (int r = 0; r < 4; r++)
                        Vb[(size_t)(rbase + r) * 1024 + (col - 2048)] = (__bf16)(v[r] + bb);
                }
            } else if (EPI == 1) {
#pragma unroll
                for (int r = 0; r < 4; r++) {
                    size_t idx = (size_t)(rbase + r) * N_TOK + col;
                    float e = __expf(mask[idx] * v[r]);
                    F8[idx] = f32_to_fp8(e - 1.0f);
                    rs[r] += e;
                }
            } else {
#pragma unroll
                for (int r = 0; r < 4; r++)
                    C[(size_t)(rbase + r) * D_DIM + col] =
                        (v[r] + colsum[col]) * (1.0f / VS_SCALE);
            }
        }
        if (EPI == 1) {
#pragma unroll
            for (int m = 1; m < 16; m <<= 1) {
#pragma unroll
                for (int r = 0; r < 4; r++) rs[r] += __shfl_xor(rs[r], m, 64);
            }
            if (l16 == 0) {
#pragma unroll
                for (int r = 0; r < 4; r++) atomicAdd(&denom[rbase + r], rs[r]);
            }
        }
    }
}

// ---------------------------------------------------------------------------
extern "C" void kernel_launch(void* const* d_in, const int* in_sizes, int n_in,
                              void* d_out, int out_size, void* d_ws, size_t ws_size,
                              hipStream_t stream) {
    const float* x    = (const float*)d_in[0];
    const float* mask = (const float*)d_in[1];
    const float* Wq   = (const float*)d_in[2];
    const float* bq   = (const float*)d_in[3];
    const float* Wk   = (const float*)d_in[4];
    const float* bk   = (const float*)d_in[5];
    const float* Wv   = (const float*)d_in[6];
    const float* bv   = (const float*)d_in[7];
    float* out = (float*)d_out;
    char* ws = (char*)d_ws;

    const size_t MB = 1024 * 1024;
    unsigned char* F8   = (unsigned char*)(ws + 0 * MB);   // 16 MB [4096][4096] fp8 (E-1)
    unsigned char* QK8  = (unsigned char*)(ws + 16 * MB);  // 8 MB [4096][2048] fp8
    __bf16*        Vb   = (__bf16*)(ws + 24 * MB);         // 8 MB [4096][1024] bf16
    unsigned char* x8   = (unsigned char*)(ws + 32 * MB);  // 4 MB [4096][1024] fp8
    unsigned char* VsT8 = x8;                              // 4 MB (reuse; x8 dead after QKV)
    unsigned char* W8T  = (unsigned char*)(ws + 36 * MB);  // 3 MB [3072][1024] fp8
    float* bcat   = (float*)(ws + 39 * MB);                // 12 KB
    float* denom  = (float*)(ws + 39 * MB + 16 * 1024);    // 16 KB [4096]
    float* colsum = (float*)(ws + 39 * MB + 32 * 1024);    // 4 KB [1024]  (contig w/ denom)

    // ---- fused prep: cvt x, transpose W, bias concat, zero denom+colsum ----
    prep<<<4896, 256, 0, stream>>>(x, x8, Wq, Wk, Wv, W8T, bq, bk, bv, bcat, denom);

    // ---- fused QKV projection: [4096][3072] = x8 @ W8T^T + bcat ----
    gemm_fp8<0, 128><<<dim3(24, 32), 256, 0, stream>>>(
        x8, W8T, 1024, 1024, D_DIM,
        bcat, nullptr, QK8, Vb, nullptr, nullptr, nullptr, nullptr);

    // ---- F = exp(mask * (Q K^T)) - 1 -> fp8; denom[row] += rowsum(e) ----
    gemm_fp8<1, 128><<<dim3(32, 32), 256, 0, stream>>>(
        QK8, QK8 + 1024, 2048, 2048, D_DIM,
        nullptr, mask, nullptr, nullptr, F8, denom, nullptr, nullptr);

    // ---- VsT8[d][j] = fp8(VS_SCALE * V[j][d]/denom[j]); colsum[d] = sum_j ----
    scale_transpose<<<dim3(16, 64), 256, 0, stream>>>(Vb, denom, VsT8, colsum);

    // ---- out = (F8 @ VsT8^T + colsum) / VS_SCALE ----
    gemm_fp8<2, 64><<<dim3(16, 32), 256, 0, stream>>>(
        F8, VsT8, 4096, 4096, N_TOK,
        nullptr, nullptr, nullptr, nullptr, nullptr, nullptr, colsum, out);
}

// Round 8
// 240.132 us; speedup vs baseline: 1.0812x; 1.0399x over previous
//
#include <hip/hip_runtime.h>
#include <hip/hip_bf16.h>

// ---------------------------------------------------------------------------
// AttentionLayer: out = quirky_softmax(mask * (Q K^T)) @ V
//   denom[j] = sum_k exp(mask[j,k]*S[j,k])  (row sums of E)
//   softmax[i,j] = E[i,j] / denom[j]        (column-indexed denom!)
//   => out = E @ Vs,  Vs[j] = V[j] / denom[j]
// R7->R8: K-loop switched to MX-scaled MFMA (mfma_scale_f32_16x16x128_f8f6f4,
// unit scales 0x7f = 2^0): one K=128 instruction replaces four 16x16x32 fp8
// MFMAs at ~2.3x the issue rate (m148: 995->1628 TF on this structure).
// Operand = the SAME two b128 LDS reads as R7 (zero-conflict pattern); the
// resulting K-permutation (lane quad q holds logical chunks {q,4+q}) is
// exact because A and B share it and all scales are equal.
// ---------------------------------------------------------------------------

#define N_TOK 4096
#define D_DIM 1024
#define VS_SCALE 131072.0f        // 2^17: lifts V/denom (~1e-5) into fp8 range

typedef float f32x4 __attribute__((ext_vector_type(4)));
typedef int   i32x4 __attribute__((ext_vector_type(4)));
typedef int   i32x8 __attribute__((ext_vector_type(8)));

typedef const __attribute__((address_space(1))) char g_char;
typedef __attribute__((address_space(3))) char lds_char;

__device__ inline unsigned char f32_to_fp8(float f) {
    return (unsigned char)(__builtin_amdgcn_cvt_pk_fp8_f32(f, f, 0, false) & 0xff);
}

// ---------------------------------------------------------------------------
// Fused prep:
//   blocks [0,4096):    x fp32 -> fp8 (4 elems/thread)
//   blocks [4096,4864): W transpose fp32 -> fp8 [out][in] (3 x 256 tiles)
//   blocks [4864,4876): bias concat
//   blocks [4876,4896): zero denom(4096)+colsum(1024) floats
// ---------------------------------------------------------------------------
__global__ void prep(const float* __restrict__ x, unsigned char* __restrict__ x8,
                     const float* __restrict__ Wq, const float* __restrict__ Wk,
                     const float* __restrict__ Wv, unsigned char* __restrict__ W8T,
                     const float* __restrict__ bq, const float* __restrict__ bk,
                     const float* __restrict__ bv, float* __restrict__ bcat,
                     float* __restrict__ zbuf) {
    __shared__ float t[64][65];
    const int b = blockIdx.x;
    const int tid = threadIdx.x;
    if (b < 4096) {
        int i = (b * 256 + tid) * 4;
        float4 v = *(const float4*)(x + i);
        unsigned int lo = (unsigned int)__builtin_amdgcn_cvt_pk_fp8_f32(v.x, v.y, 0, false);
        unsigned int pk = (unsigned int)__builtin_amdgcn_cvt_pk_fp8_f32(v.z, v.w, (int)lo, true);
        *(unsigned int*)(x8 + i) = pk;
    } else if (b < 4864) {
        const int b2 = b - 4096;
        const int z = b2 >> 8;              // which W
        const int rem = b2 & 255;
        const float* in = (z == 0) ? Wq : (z == 1) ? Wk : Wv;
        unsigned char* oT = W8T + (size_t)z * 1024 * 1024;
        const int c0 = (rem & 15) * 64, r0 = (rem >> 4) * 64;
#pragma unroll
        for (int k = 0; k < 16; k++) {
            int lin = tid + k * 256;
            int r = lin >> 6, c = lin & 63;
            t[r][c] = in[(size_t)(r0 + r) * 1024 + c0 + c];
        }
        __syncthreads();
#pragma unroll
        for (int k = 0; k < 16; k++) {
            int lin = tid + k * 256;
            int c = lin >> 6, r = lin & 63;
            oT[(size_t)(c0 + c) * 1024 + r0 + r] = f32_to_fp8(t[r][c]);
        }
    } else if (b < 4876) {
        int i = (b - 4864) * 256 + tid;
        if (i < 1024) bcat[i] = bq[i];
        else if (i < 2048) bcat[i] = bk[i - 1024];
        else if (i < 3072) bcat[i] = bv[i - 2048];
    } else {
        zbuf[(b - 4876) * 256 + tid] = 0.0f;
    }
}

// ---------------------------------------------------------------------------
// VsT8[d][j] = fp8( VS_SCALE * V[j][d] / denom[j] );  colsum[d] += sum_j vs
// ---------------------------------------------------------------------------
__global__ void scale_transpose(const __bf16* __restrict__ V,
                                const float* __restrict__ denom,
                                unsigned char* __restrict__ VT8,
                                float* __restrict__ colsum) {
    __shared__ float t[64][65];
    __shared__ float rd[64];
    const int d0 = blockIdx.x * 64, j0 = blockIdx.y * 64;
    const int tid = threadIdx.x;
    const int lane = tid & 63;
    if (tid < 64) rd[tid] = VS_SCALE / denom[j0 + tid];
    __syncthreads();
#pragma unroll
    for (int k = 0; k < 16; k++) {
        int lin = tid + k * 256;
        int j = lin >> 6, d = lin & 63;
        t[j][d] = (float)V[(size_t)(j0 + j) * D_DIM + d0 + d] * rd[j];
    }
    __syncthreads();
#pragma unroll
    for (int k = 0; k < 16; k++) {
        int d = (tid >> 6) + k * 4;   // wave-uniform
        float val = t[lane][d];
        VT8[(size_t)(d0 + d) * N_TOK + j0 + lane] = f32_to_fp8(val);
#pragma unroll
        for (int m = 1; m < 64; m <<= 1) val += __shfl_xor(val, m, 64);
        if (lane == 0) atomicAdd(&colsum[d0 + d], val);
    }
}

// ---------------------------------------------------------------------------
// Unified fp8 NT GEMM: C = A * B^T, fp8 e4m3 in, fp32 acc, BK=128.
// 128 x TN tile, 4 waves as 2x2, each 64 x TN/2 (4 x NF frags).
// LDS: row = 128 B = 8 x 16B chunks; chunk q of row r stored at q^(r&7)
// (XOR swizzle on the staging SOURCE address; zero-conflict, R7-verified).
// K-loop: one mfma_scale_f32_16x16x128_f8f6f4 per frag pair, unit scales.
// Lane operand = b128 at ((quad)^l7)*16  ++  b128 at ((4+quad)^l7)*16
// = logical chunks {quad, 4+quad}; identical K-permutation for A and B with
// equal scales => exact contraction.
// EPI 0 (QKV):  cols<2048 -> QK8 fp8 (+bias), else -> Vb bf16 (+bias)
// EPI 1 (E):    e=exp(mask*acc); F8=fp8(e-1); denom[row]+=rowsum(e) atomics
// EPI 2 (out):  C = (acc + colsum[col]) / VS_SCALE
// ---------------------------------------------------------------------------
template <int EPI, int TN>
__global__ __launch_bounds__(256, 4)
void gemm_fp8(const unsigned char* __restrict__ A, const unsigned char* __restrict__ B,
              int sA, int sB, int K,               // row strides in BYTES
              const float* __restrict__ bias,
              const float* __restrict__ mask,
              unsigned char* __restrict__ QK8, __bf16* __restrict__ Vb,
              unsigned char* __restrict__ F8, float* __restrict__ denom,
              const float* __restrict__ colsum, float* __restrict__ C) {
    constexpr int NF = TN / 32;                    // B frags per wave
    constexpr int BP = TN / 32;                    // B staging passes
    __shared__ __align__(16) unsigned char lA[128 * 128];
    __shared__ __align__(16) unsigned char lB[TN * 128];

    const int tid  = threadIdx.x;
    const int wave = tid >> 6;
    const int lane = tid & 63;
    const int quad = lane >> 4;
    const int l16  = lane & 15;
    const int m0 = blockIdx.y * 128;
    const int n0 = blockIdx.x * TN;
    const int wr = (wave >> 1) * 64;
    const int wc = (wave & 1) * (TN / 2);

    // staging source (swizzled): thread handles row tr, 16B chunk (tid&7)^(tr&7)
    const int tr = tid >> 3;
    const int ts = ((tid & 7) ^ (tr & 7)) * 16;
    const char* gA = (const char*)A + (size_t)(m0 + tr) * sA + ts;
    const char* gB = (const char*)B + (size_t)(n0 + tr) * sB + ts;
    const size_t pstepA = (size_t)32 * sA;
    const size_t pstepB = (size_t)32 * sB;

    lds_char* lAp = (lds_char*)(void*)lA + wave * 1024;
    lds_char* lBp = (lds_char*)(void*)lB + wave * 1024;

    // b128 read offsets: aligned half-row groups {0..3}^l7 and {4..7}^l7
    const int l7 = l16 & 7;
    const int rdp0 = ((0 + quad) ^ l7) * 16;
    const int rdp1 = ((4 + quad) ^ l7) * 16;

    f32x4 acc[4][NF];
#pragma unroll
    for (int i = 0; i < 4; i++)
#pragma unroll
        for (int j = 0; j < NF; j++) acc[i][j] = (f32x4){0.f, 0.f, 0.f, 0.f};

    for (int kt = 0; kt < K; kt += 128) {
#pragma unroll
        for (int c = 0; c < 4; c++)
            __builtin_amdgcn_global_load_lds((g_char*)(gA + c * pstepA),
                                             lAp + c * 4096, 16, 0, 0);
#pragma unroll
        for (int c = 0; c < BP; c++)
            __builtin_amdgcn_global_load_lds((g_char*)(gB + c * pstepB),
                                             lBp + c * 4096, 16, 0, 0);
        gA += 128;
        gB += 128;
        __syncthreads();

        i32x4 alo[4], ahi[4], blo[NF], bhi[NF];
#pragma unroll
        for (int i = 0; i < 4; i++) {
            const unsigned char* rp = &lA[(wr + i * 16 + l16) * 128];
            alo[i] = *(const i32x4*)(rp + rdp0);
            ahi[i] = *(const i32x4*)(rp + rdp1);
        }
#pragma unroll
        for (int j = 0; j < NF; j++) {
            const unsigned char* rp = &lB[(wc + j * 16 + l16) * 128];
            blo[j] = *(const i32x4*)(rp + rdp0);
            bhi[j] = *(const i32x4*)(rp + rdp1);
        }
#pragma unroll
        for (int i = 0; i < 4; i++) {
            i32x8 a8 = __builtin_shufflevector(alo[i], ahi[i], 0, 1, 2, 3, 4, 5, 6, 7);
#pragma unroll
            for (int j = 0; j < NF; j++) {
                i32x8 b8 = __builtin_shufflevector(blo[j], bhi[j], 0, 1, 2, 3, 4, 5, 6, 7);
                acc[i][j] = __builtin_amdgcn_mfma_scale_f32_16x16x128_f8f6f4(
                    a8, b8, acc[i][j], 0, 0,       // cbsz=0 (fp8), blgp=0 (fp8)
                    0, 0x7f7f7f7f,                 // scale A: all-bytes 127 = 2^0
                    0, 0x7f7f7f7f);                // scale B: 2^0
            }
        }
        __syncthreads();
    }

    // epilogue: C/D layout col=lane&15, row=quad*4+reg (shape-determined)
#pragma unroll
    for (int i = 0; i < 4; i++) {
        const int rbase = m0 + wr + i * 16 + quad * 4;
        f32x4 rs = (f32x4){0.f, 0.f, 0.f, 0.f};
#pragma unroll
        for (int j = 0; j < NF; j++) {
            const int col = n0 + wc + j * 16 + l16;
            f32x4 v = acc[i][j];
            if (EPI == 0) {
                const float bb = bias[col];
                if (n0 < 2048) {   // Q/K region -> fp8, row stride 2048
#pragma unroll
                    for (int r = 0; r < 4; r++)
                        QK8[(size_t)(rbase + r) * 2048 + col] = f32_to_fp8(v[r] + bb);
                } else {           // V region -> bf16, row stride 1024
#pragma unroll
                    for (int r = 0; r < 4; r++)
                        Vb[(size_t)(rbase + r) * 1024 + (col - 2048)] = (__bf16)(v[r] + bb);
                }
            } else if (EPI == 1) {
#pragma unroll
                for (int r = 0; r < 4; r++) {
                    size_t idx = (size_t)(rbase + r) * N_TOK + col;
                    float e = __expf(mask[idx] * v[r]);
                    F8[idx] = f32_to_fp8(e - 1.0f);
                    rs[r] += e;
                }
            } else {
#pragma unroll
                for (int r = 0; r < 4; r++)
                    C[(size_t)(rbase + r) * D_DIM + col] =
                        (v[r] + colsum[col]) * (1.0f / VS_SCALE);
            }
        }
        if (EPI == 1) {
#pragma unroll
            for (int m = 1; m < 16; m <<= 1) {
#pragma unroll
                for (int r = 0; r < 4; r++) rs[r] += __shfl_xor(rs[r], m, 64);
            }
            if (l16 == 0) {
#pragma unroll
                for (int r = 0; r < 4; r++) atomicAdd(&denom[rbase + r], rs[r]);
            }
        }
    }
}

// ---------------------------------------------------------------------------
extern "C" void kernel_launch(void* const* d_in, const int* in_sizes, int n_in,
                              void* d_out, int out_size, void* d_ws, size_t ws_size,
                              hipStream_t stream) {
    const float* x    = (const float*)d_in[0];
    const float* mask = (const float*)d_in[1];
    const float* Wq   = (const float*)d_in[2];
    const float* bq   = (const float*)d_in[3];
    const float* Wk   = (const float*)d_in[4];
    const float* bk   = (const float*)d_in[5];
    const float* Wv   = (const float*)d_in[6];
    const float* bv   = (const float*)d_in[7];
    float* out = (float*)d_out;
    char* ws = (char*)d_ws;

    const size_t MB = 1024 * 1024;
    unsigned char* F8   = (unsigned char*)(ws + 0 * MB);   // 16 MB [4096][4096] fp8 (E-1)
    unsigned char* QK8  = (unsigned char*)(ws + 16 * MB);  // 8 MB [4096][2048] fp8
    __bf16*        Vb   = (__bf16*)(ws + 24 * MB);         // 8 MB [4096][1024] bf16
    unsigned char* x8   = (unsigned char*)(ws + 32 * MB);  // 4 MB [4096][1024] fp8
    unsigned char* VsT8 = x8;                              // 4 MB (reuse; x8 dead after QKV)
    unsigned char* W8T  = (unsigned char*)(ws + 36 * MB);  // 3 MB [3072][1024] fp8
    float* bcat   = (float*)(ws + 39 * MB);                // 12 KB
    float* denom  = (float*)(ws + 39 * MB + 16 * 1024);    // 16 KB [4096]
    float* colsum = (float*)(ws + 39 * MB + 32 * 1024);    // 4 KB [1024]  (contig w/ denom)

    // ---- fused prep: cvt x, transpose W, bias concat, zero denom+colsum ----
    prep<<<4896, 256, 0, stream>>>(x, x8, Wq, Wk, Wv, W8T, bq, bk, bv, bcat, denom);

    // ---- fused QKV projection: [4096][3072] = x8 @ W8T^T + bcat ----
    gemm_fp8<0, 128><<<dim3(24, 32), 256, 0, stream>>>(
        x8, W8T, 1024, 1024, D_DIM,
        bcat, nullptr, QK8, Vb, nullptr, nullptr, nullptr, nullptr);

    // ---- F = exp(mask * (Q K^T)) - 1 -> fp8; denom[row] += rowsum(e) ----
    gemm_fp8<1, 128><<<dim3(32, 32), 256, 0, stream>>>(
        QK8, QK8 + 1024, 2048, 2048, D_DIM,
        nullptr, mask, nullptr, nullptr, F8, denom, nullptr, nullptr);

    // ---- VsT8[d][j] = fp8(VS_SCALE * V[j][d]/denom[j]); colsum[d] = sum_j ----
    scale_transpose<<<dim3(16, 64), 256, 0, stream>>>(Vb, denom, VsT8, colsum);

    // ---- out = (F8 @ VsT8^T + colsum) / VS_SCALE ----
    gemm_fp8<2, 64><<<dim3(16, 32), 256, 0, stream>>>(
        F8, VsT8, 4096, 4096, N_TOK,
        nullptr, nullptr, nullptr, nullptr, nullptr, nullptr, colsum, out);
}